// Round 1
// baseline (442.936 us; speedup 1.0000x reference)
//
#include <hip/hip_runtime.h>
#include <hip/hip_bf16.h>

#define HIDDEN 1024
#define INTER  704
#define W1COLS (2*INTER)   // 1408
#define NEXP   32

#define TM  128
#define BK  64
#define LDK (BK + 8)       // padded LDS row stride (elems); 144 B, 16B-aligned

typedef __attribute__((ext_vector_type(8))) short bf16x8;
typedef __attribute__((ext_vector_type(4))) float f32x4;

__device__ __forceinline__ unsigned short f2bf(float f) {
    union { float f; unsigned u; } v; v.f = f;
    unsigned r = v.u + 0x7FFF + ((v.u >> 16) & 1);   // RNE
    return (unsigned short)(r >> 16);
}

__device__ __forceinline__ float fcomp(const float4& v, int c) {
    return c == 0 ? v.x : c == 1 ? v.y : c == 2 ? v.z : v.w;
}

// map block m-index -> (expert, global row0, valid rows) over ragged groups
__device__ __forceinline__ bool map_tile(const int* s_tpe, int bm,
                                         int& row0, int& rows, int& e) {
    int start = 0, rem = bm;
    for (int i = 0; i < NEXP; ++i) {
        int g = s_tpe[i];
        int nt = (g + TM - 1) / TM;
        if (rem < nt) { row0 = start + rem * TM; rows = min(TM, g - rem * TM); e = i; return true; }
        rem -= nt; start += g;
    }
    return false;
}

// ---------------- GEMM1 + SwiGLU:  h = silu(x@w1) * (x@w3)  ----------------
// block tile: 128 rows x (64 gate cols + 64 up cols), BK=64, 4 waves
__global__ __launch_bounds__(256, 2)
void gemm1_swiglu(const float* __restrict__ x, const int* __restrict__ tpe,
                  const float* __restrict__ w1w3, unsigned short* __restrict__ h)
{
    __shared__ int s_tpe[NEXP];
    __shared__ unsigned short sA[TM][LDK];   // [m][k] bf16
    __shared__ unsigned short sB[128][LDK];  // [n][k] bf16, n<64 gate, n>=64 up

    int t = threadIdx.x;
    if (t < NEXP) s_tpe[t] = tpe[t];
    __syncthreads();

    int row0, rows, e;
    if (!map_tile(s_tpe, blockIdx.x, row0, rows, e)) return;
    int jb = blockIdx.y;  // 0..10, 64 INTER cols each

    // A staging: thread -> row ar, k-half ak (32 floats = 8 float4)
    int ar = t >> 1;
    int ak = (t & 1) * 32;
    // B staging: thread -> 4 cols x 8 k rows micro-block
    int bn = (t & 31) * 4;     // 0..124 (block-local col)
    int bk = (t >> 5) * 8;     // 0..56
    int gcol = (bn < 64) ? (jb * 64 + bn) : (INTER + jb * 64 + (bn - 64));

    const float* aptr = x + (size_t)(row0 + ar) * HIDDEN + ak;
    const float* bptr = w1w3 + (size_t)e * HIDDEN * W1COLS + (size_t)bk * W1COLS + gcol;

    int wv = t >> 6, lane = t & 63, l16 = lane & 15, quad = lane >> 4;

    f32x4 accg[2][4], accu[2][4];
    #pragma unroll
    for (int i = 0; i < 2; i++)
        #pragma unroll
        for (int j = 0; j < 4; j++) { accg[i][j] = (f32x4)(0.f); accu[i][j] = (f32x4)(0.f); }

    for (int ko = 0; ko < HIDDEN; ko += BK) {
        // ---- global loads into regs (overlap with prior compute) ----
        float4 av[8];
        if (ar < rows) {
            const float4* p = (const float4*)(aptr + ko);
            #pragma unroll
            for (int j = 0; j < 8; j++) av[j] = p[j];
        } else {
            #pragma unroll
            for (int j = 0; j < 8; j++) av[j] = make_float4(0.f, 0.f, 0.f, 0.f);
        }
        float4 bv[8];
        {
            const float* p = bptr + (size_t)ko * W1COLS;
            #pragma unroll
            for (int j = 0; j < 8; j++) bv[j] = *(const float4*)(p + (size_t)j * W1COLS);
        }

        __syncthreads();   // prior iter's LDS reads done

        // ---- write A tile (bf16) ----
        {
            uint4* dst = (uint4*)&sA[ar][ak];
            #pragma unroll
            for (int c = 0; c < 4; c++) {
                float4 a = av[2 * c], b = av[2 * c + 1];
                uint4 vv;
                vv.x = (unsigned)f2bf(a.x) | ((unsigned)f2bf(a.y) << 16);
                vv.y = (unsigned)f2bf(a.z) | ((unsigned)f2bf(a.w) << 16);
                vv.z = (unsigned)f2bf(b.x) | ((unsigned)f2bf(b.y) << 16);
                vv.w = (unsigned)f2bf(b.z) | ((unsigned)f2bf(b.w) << 16);
                dst[c] = vv;
            }
        }
        // ---- write B tile transposed ----
        #pragma unroll
        for (int c = 0; c < 4; c++) {
            uint4 vv;
            vv.x = (unsigned)f2bf(fcomp(bv[0], c)) | ((unsigned)f2bf(fcomp(bv[1], c)) << 16);
            vv.y = (unsigned)f2bf(fcomp(bv[2], c)) | ((unsigned)f2bf(fcomp(bv[3], c)) << 16);
            vv.z = (unsigned)f2bf(fcomp(bv[4], c)) | ((unsigned)f2bf(fcomp(bv[5], c)) << 16);
            vv.w = (unsigned)f2bf(fcomp(bv[6], c)) | ((unsigned)f2bf(fcomp(bv[7], c)) << 16);
            *(uint4*)&sB[bn + c][bk] = vv;
        }
        __syncthreads();

        // ---- MFMA ----
        #pragma unroll
        for (int kk = 0; kk < 2; ++kk) {
            int kb = kk * 32 + quad * 8;
            bf16x8 afr[2];
            afr[0] = *(const bf16x8*)&sA[wv * 32 + l16][kb];
            afr[1] = *(const bf16x8*)&sA[wv * 32 + 16 + l16][kb];
            #pragma unroll
            for (int ct = 0; ct < 4; ++ct) {
                bf16x8 bg = *(const bf16x8*)&sB[ct * 16 + l16][kb];
                bf16x8 bu = *(const bf16x8*)&sB[64 + ct * 16 + l16][kb];
                #pragma unroll
                for (int rt = 0; rt < 2; ++rt) {
                    accg[rt][ct] = __builtin_amdgcn_mfma_f32_16x16x32_bf16(afr[rt], bg, accg[rt][ct], 0, 0, 0);
                    accu[rt][ct] = __builtin_amdgcn_mfma_f32_16x16x32_bf16(afr[rt], bu, accu[rt][ct], 0, 0, 0);
                }
            }
        }
    }

    // ---- epilogue: SwiGLU, store h (bf16) ----
    #pragma unroll
    for (int rt = 0; rt < 2; ++rt) {
        #pragma unroll
        for (int reg = 0; reg < 4; ++reg) {
            int rl = wv * 32 + rt * 16 + quad * 4 + reg;
            if (rl < rows) {
                size_t grow = (size_t)(row0 + rl);
                #pragma unroll
                for (int ct = 0; ct < 4; ++ct) {
                    int gc = jb * 64 + ct * 16 + l16;
                    float g = accg[rt][ct][reg];
                    float u = accu[rt][ct][reg];
                    float s = g / (1.f + __expf(-g)) * u;
                    h[grow * INTER + gc] = f2bf(s);
                }
            }
        }
    }
}

// ---------------- GEMM2:  out = h @ w2  ----------------
__global__ __launch_bounds__(256, 2)
void gemm2(const unsigned short* __restrict__ h, const int* __restrict__ tpe,
           const float* __restrict__ w2, float* __restrict__ out)
{
    __shared__ int s_tpe[NEXP];
    __shared__ unsigned short sA[TM][LDK];
    __shared__ unsigned short sB[64][LDK];

    int t = threadIdx.x;
    if (t < NEXP) s_tpe[t] = tpe[t];
    __syncthreads();

    int row0, rows, e;
    if (!map_tile(s_tpe, blockIdx.x, row0, rows, e)) return;
    int jb = blockIdx.y;  // 0..15

    int ar = t >> 1, ak = (t & 1) * 32;
    int bn = (t & 15) * 4;   // 0..60
    int bk = (t >> 4) * 4;   // 0..60

    const unsigned short* aptr = h + (size_t)(row0 + ar) * INTER + ak;
    const float* bptr = w2 + (size_t)e * INTER * HIDDEN + (size_t)bk * HIDDEN + jb * 64 + bn;

    int wv = t >> 6, lane = t & 63, l16 = lane & 15, quad = lane >> 4;

    f32x4 acc[2][4];
    #pragma unroll
    for (int i = 0; i < 2; i++)
        #pragma unroll
        for (int j = 0; j < 4; j++) acc[i][j] = (f32x4)(0.f);

    for (int ko = 0; ko < INTER; ko += BK) {   // 11 iters
        uint4 av[4];
        if (ar < rows) {
            const uint4* p = (const uint4*)(aptr + ko);
            #pragma unroll
            for (int j = 0; j < 4; j++) av[j] = p[j];
        } else {
            #pragma unroll
            for (int j = 0; j < 4; j++) av[j] = make_uint4(0u, 0u, 0u, 0u);
        }
        float4 bv[4];
        {
            const float* p = bptr + (size_t)ko * HIDDEN;
            #pragma unroll
            for (int j = 0; j < 4; j++) bv[j] = *(const float4*)(p + (size_t)j * HIDDEN);
        }

        __syncthreads();
        {
            uint4* dst = (uint4*)&sA[ar][ak];
            #pragma unroll
            for (int j = 0; j < 4; j++) dst[j] = av[j];
        }
        #pragma unroll
        for (int c = 0; c < 4; c++) {
            uint2 vv;
            vv.x = (unsigned)f2bf(fcomp(bv[0], c)) | ((unsigned)f2bf(fcomp(bv[1], c)) << 16);
            vv.y = (unsigned)f2bf(fcomp(bv[2], c)) | ((unsigned)f2bf(fcomp(bv[3], c)) << 16);
            *(uint2*)&sB[bn + c][bk] = vv;
        }
        __syncthreads();

        #pragma unroll
        for (int kk = 0; kk < 2; ++kk) {
            int kb = kk * 32 + quad * 8;
            bf16x8 afr[2];
            afr[0] = *(const bf16x8*)&sA[wv * 32 + l16][kb];
            afr[1] = *(const bf16x8*)&sA[wv * 32 + 16 + l16][kb];
            #pragma unroll
            for (int ct = 0; ct < 4; ++ct) {
                bf16x8 bf = *(const bf16x8*)&sB[ct * 16 + l16][kb];
                #pragma unroll
                for (int rt = 0; rt < 2; ++rt) {
                    acc[rt][ct] = __builtin_amdgcn_mfma_f32_16x16x32_bf16(afr[rt], bf, acc[rt][ct], 0, 0, 0);
                }
            }
        }
    }

    #pragma unroll
    for (int rt = 0; rt < 2; ++rt) {
        #pragma unroll
        for (int reg = 0; reg < 4; ++reg) {
            int rl = wv * 32 + rt * 16 + quad * 4 + reg;
            if (rl < rows) {
                size_t grow = (size_t)(row0 + rl);
                #pragma unroll
                for (int ct = 0; ct < 4; ++ct) {
                    out[grow * HIDDEN + jb * 64 + ct * 16 + l16] = acc[rt][ct][reg];
                }
            }
        }
    }
}

extern "C" void kernel_launch(void* const* d_in, const int* in_sizes, int n_in,
                              void* d_out, int out_size, void* d_ws, size_t ws_size,
                              hipStream_t stream) {
    const float* x     = (const float*)d_in[0];
    const int*   tpe   = (const int*)d_in[1];
    const float* w1w3  = (const float*)d_in[2];
    const float* w2    = (const float*)d_in[3];
    float* out = (float*)d_out;
    unsigned short* h = (unsigned short*)d_ws;   // [8192][704] bf16, 11.5 MB

    dim3 blk(256);
    dim3 g1(96, INTER / 64);    // 96 m-tiles max, 11 n-tiles
    dim3 g2(96, HIDDEN / 64);   // 96 m-tiles max, 16 n-tiles
    hipLaunchKernelGGL(gemm1_swiglu, g1, blk, 0, stream, x, tpe, w1w3, h);
    hipLaunchKernelGGL(gemm2, g2, blk, 0, stream, h, tpe, w2, out);
}